// Round 1
// baseline (442.215 us; speedup 1.0000x reference)
//
#include <hip/hip_runtime.h>
#include <math.h>

// Problem constants: B=8, C=256, H=W=64
#define HW   4096
#define CC   256
#define NPIX 32768

// ws layout (float offsets). Total ~8.89M floats = 35.5 MB.
// fe buffer is reused for agg (fe dead after k_sim).
#define OFS_FE   0ul
#define OFS_SIM  8388608ul   // 8*9*4096
#define OFS_WT1  8683520ul   // 256*256 folded+transposed embed weights
#define OFS_B1   8749056ul   // 256
#define OFS_WT2  8749312ul   // 512*256 folded+transposed enhance weights
#define OFS_B2   8880384ul   // 256
#define OFS_POOL 8880640ul   // 8*512
#define OFS_GATE 8884736ul   // 8*256

// ---------------- prep: fold BN into transposed weights ----------------
__global__ __launch_bounds__(256) void k_prep(
    const float* __restrict__ w1, const float* __restrict__ b1,
    const float* __restrict__ g1, const float* __restrict__ be1,
    const float* __restrict__ m1, const float* __restrict__ v1,
    const float* __restrict__ w2, const float* __restrict__ b2,
    const float* __restrict__ g2, const float* __restrict__ be2,
    const float* __restrict__ m2, const float* __restrict__ v2,
    float* __restrict__ ws)
{
    int idx = blockIdx.x * 256 + threadIdx.x;
    if (idx < 65536) {                      // wT1[c][o] = w1[o][c]*inv1[o]
        int o = idx & 255, c = idx >> 8;
        float inv = g1[o] * rsqrtf(v1[o] + 1e-5f);
        ws[OFS_WT1 + idx] = w1[o * 256 + c] * inv;
    } else if (idx < 196608) {              // wT2[c][o] = w2[o][c]*inv2[o]
        int j = idx - 65536;
        int o = j & 255, c = j >> 8;
        float inv = g2[o] * rsqrtf(v2[o] + 1e-5f);
        ws[OFS_WT2 + j] = w2[o * 512 + c] * inv;
    } else if (idx < 196864) {
        int o = idx - 196608;
        float inv = g1[o] * rsqrtf(v1[o] + 1e-5f);
        ws[OFS_B1 + o] = b1[o] * inv + be1[o] - m1[o] * inv;
    } else if (idx < 197120) {
        int o = idx - 196864;
        float inv = g2[o] * rsqrtf(v2[o] + 1e-5f);
        ws[OFS_B2 + o] = b2[o] * inv + be2[o] - m2[o] * inv;
    }
}

// ---------------- GEMM (1x1 conv) + bias + ReLU ----------------
// 64 pixels x 256 outs per block, 8x8 micro-tile per thread, K chunks of 32.
// Weights read from global (pre-transposed wT[c][o], L1-resident);
// x tile staged in LDS. in1 supplies channels >= 256 (concat input).
template<int KIN>
__global__ __launch_bounds__(256) void k_gemm(
    const float* __restrict__ in0, const float* __restrict__ in1,
    const float* __restrict__ wT, const float* __restrict__ biasf,
    float* __restrict__ out)
{
    __shared__ float xs[32][64];
    const int t = threadIdx.x;
    const int tx = t & 7, ty = t >> 3;
    const int p0 = blockIdx.x * 64;
    const int b = p0 >> 12, pin = p0 & 4095;
    const int o0 = ty * 8, px0 = tx * 8;
    float acc[8][8] = {};

    for (int kc = 0; kc < KIN / 32; ++kc) {
        const int cbase = kc * 32;
        const float* src = (cbase < 256)
            ? in0 + (size_t)(b * 256 + cbase) * HW + pin
            : in1 + (size_t)(b * 256 + (cbase - 256)) * HW + pin;
        __syncthreads();
#pragma unroll
        for (int i = 0; i < 8; ++i) {
            int idx = i * 256 + t;
            int cl = idx >> 6, pp = idx & 63;
            xs[cl][pp] = src[cl * HW + pp];
        }
        __syncthreads();
        const float* wp = wT + (size_t)cbase * CC + o0;
#pragma unroll
        for (int c = 0; c < 32; ++c) {
            float4 xv0 = *(const float4*)&xs[c][px0];
            float4 xv1 = *(const float4*)&xs[c][px0 + 4];
            float4 wv0 = *(const float4*)(wp + c * CC);
            float4 wv1 = *(const float4*)(wp + c * CC + 4);
            float xr[8] = {xv0.x, xv0.y, xv0.z, xv0.w, xv1.x, xv1.y, xv1.z, xv1.w};
            float wr[8] = {wv0.x, wv0.y, wv0.z, wv0.w, wv1.x, wv1.y, wv1.z, wv1.w};
#pragma unroll
            for (int i = 0; i < 8; ++i)
#pragma unroll
                for (int j = 0; j < 8; ++j)
                    acc[i][j] = fmaf(wr[i], xr[j], acc[i][j]);
        }
    }
#pragma unroll
    for (int i = 0; i < 8; ++i) {
        const int o = o0 + i;
        const float bia = biasf[o];
        float4 s0, s1;
        s0.x = fmaxf(acc[i][0] + bia, 0.f);
        s0.y = fmaxf(acc[i][1] + bia, 0.f);
        s0.z = fmaxf(acc[i][2] + bia, 0.f);
        s0.w = fmaxf(acc[i][3] + bia, 0.f);
        s1.x = fmaxf(acc[i][4] + bia, 0.f);
        s1.y = fmaxf(acc[i][5] + bia, 0.f);
        s1.z = fmaxf(acc[i][6] + bia, 0.f);
        s1.w = fmaxf(acc[i][7] + bia, 0.f);
        float* op = out + (size_t)(b * 256 + o) * HW + pin + px0;
        *(float4*)op = s0;
        *(float4*)(op + 4) = s1;
    }
}

// ---------------- region cosine similarity + softmax ----------------
// One block per (b,h) row: 64 pixels, channels split 4 ways across slices.
__global__ __launch_bounds__(256) void k_sim(
    const float* __restrict__ fe, float* __restrict__ sim)
{
    __shared__ float red[4][64][18];
    const int t = threadIdx.x;
    const int w = t & 63, sl = t >> 6;
    const int r = blockIdx.x;
    const int b = r >> 6, h = r & 63;

    const int hh[3] = {h > 0 ? h - 1 : 0, h, h < 63 ? h + 1 : 63};
    const float mh[3] = {h > 0 ? 1.f : 0.f, 1.f, h < 63 ? 1.f : 0.f};
    const int wcl[3] = {w > 0 ? w - 1 : 0, w, w < 63 ? w + 1 : 63};
    const float mwv[3] = {w > 0 ? 1.f : 0.f, 1.f, w < 63 ? 1.f : 0.f};
    int offs[9];
    float msk[9];
#pragma unroll
    for (int i = 0; i < 3; ++i)
#pragma unroll
        for (int j = 0; j < 3; ++j) {
            offs[i * 3 + j] = hh[i] * 64 + wcl[j];
            msk[i * 3 + j] = mh[i] * mwv[j];
        }

    const float* base = fe + (size_t)(b * 256 + sl * 64) * HW;
    float dot[9] = {};
    float np[9] = {};
#pragma unroll 4
    for (int ci = 0; ci < 64; ++ci) {
        const float* p = base + ci * HW;
        float v[9];
#pragma unroll
        for (int k = 0; k < 9; ++k) v[k] = p[offs[k]] * msk[k];
        const float c0 = v[4];
#pragma unroll
        for (int k = 0; k < 9; ++k) {
            dot[k] = fmaf(c0, v[k], dot[k]);
            np[k] = fmaf(v[k], v[k], np[k]);
        }
    }
#pragma unroll
    for (int k = 0; k < 9; ++k) {
        red[sl][w][k] = dot[k];
        red[sl][w][9 + k] = np[k];
    }
    __syncthreads();
    if (t < 64) {
        float d[9], n[9];
#pragma unroll
        for (int k = 0; k < 9; ++k) {
            d[k] = red[0][w][k] + red[1][w][k] + red[2][w][k] + red[3][w][k];
            n[k] = red[0][w][9 + k] + red[1][w][9 + k] + red[2][w][9 + k] + red[3][w][9 + k];
        }
        const float nc = sqrtf(n[4]);
        float s[9];
#pragma unroll
        for (int k = 0; k < 9; ++k) s[k] = d[k] / (nc * sqrtf(n[k]) + 1e-7f);
        float mx = s[0];
#pragma unroll
        for (int k = 1; k < 9; ++k) mx = fmaxf(mx, s[k]);
        float e[9], sum = 0.f;
#pragma unroll
        for (int k = 0; k < 9; ++k) { e[k] = expf(s[k] - mx); sum += e[k]; }
        const float rs = 1.f / sum;
#pragma unroll
        for (int k = 0; k < 9; ++k)
            sim[(size_t)(b * 9 + k) * HW + h * 64 + w] = e[k] * rs;
    }
}

// ---------------- dynamic aggregation on original x ----------------
__global__ __launch_bounds__(256) void k_agg(
    const float* __restrict__ x, const float* __restrict__ sim,
    float* __restrict__ agg)
{
    __shared__ float simbuf[9][64];
    const int t = threadIdx.x;
    const int r = blockIdx.x;
    const int b = r >> 6, h = r & 63;
    for (int i = t; i < 576; i += 256) {
        int k = i >> 6, ww = i & 63;
        simbuf[k][ww] = sim[(size_t)(b * 9 + k) * HW + h * 64 + ww];
    }
    __syncthreads();
    const int w = t & 63, cg = t >> 6;
    const int hh[3] = {h > 0 ? h - 1 : 0, h, h < 63 ? h + 1 : 63};
    const float mh[3] = {h > 0 ? 1.f : 0.f, 1.f, h < 63 ? 1.f : 0.f};
    const int wcl[3] = {w > 0 ? w - 1 : 0, w, w < 63 ? w + 1 : 63};
    const float mwv[3] = {w > 0 ? 1.f : 0.f, 1.f, w < 63 ? 1.f : 0.f};
    int offs[9];
    float ms[9];
#pragma unroll
    for (int i = 0; i < 3; ++i)
#pragma unroll
        for (int j = 0; j < 3; ++j) {
            offs[i * 3 + j] = hh[i] * 64 + wcl[j];
            ms[i * 3 + j] = mh[i] * mwv[j] * simbuf[i * 3 + j][w];
        }
#pragma unroll 2
    for (int c = cg; c < 256; c += 4) {
        const float* p = x + (size_t)(b * 256 + c) * HW;
        float s = 0.f;
#pragma unroll
        for (int k = 0; k < 9; ++k) s = fmaf(p[offs[k]], ms[k], s);
        agg[(size_t)(b * 256 + c) * HW + h * 64 + w] = s;
    }
}

// ---------------- global average pool of concat([x, enhanced]) ----------------
__global__ __launch_bounds__(256) void k_pool(
    const float* __restrict__ x, const float* __restrict__ enh,
    float* __restrict__ pool)
{
    const int t = threadIdx.x;
    const int g = blockIdx.x * 4 + (t >> 6);   // (b,channel) pair, 4096 total
    const int lane = t & 63;
    const int b = g >> 9, j = g & 511;
    const float* src = (j < 256) ? x + (size_t)(b * 256 + j) * HW
                                 : enh + (size_t)(b * 256 + j - 256) * HW;
    float s = 0.f;
    for (int i = 0; i < 64; ++i) s += src[lane + i * 64];
    for (int off = 32; off > 0; off >>= 1) s += __shfl_down(s, off, 64);
    if (lane == 0) pool[g] = s * (1.f / 4096.f);
}

// ---------------- SE-style gate MLP ----------------
__global__ __launch_bounds__(64) void k_mlp(
    const float* __restrict__ pool,
    const float* __restrict__ wg1, const float* __restrict__ bg1,
    const float* __restrict__ wg2, const float* __restrict__ bg2,
    float* __restrict__ gate)
{
    __shared__ float pl[512];
    __shared__ float hb[64];
    const int b = blockIdx.x, t = threadIdx.x;
    for (int i = t; i < 512; i += 64) pl[i] = pool[b * 512 + i];
    __syncthreads();
    float s = bg1[t];
    const float* wr = wg1 + t * 512;
    for (int c = 0; c < 512; ++c) s = fmaf(wr[c], pl[c], s);
    hb[t] = fmaxf(s, 0.f);
    __syncthreads();
#pragma unroll
    for (int rr = 0; rr < 4; ++rr) {
        const int o = t + rr * 64;
        float s2 = bg2[o];
        const float* w2 = wg2 + o * 64;
        for (int j = 0; j < 64; ++j) s2 = fmaf(w2[j], hb[j], s2);
        gate[b * 256 + o] = 1.f / (1.f + expf(-s2));
    }
}

// ---------------- final: out = x + gate * enhanced (in-place on d_out) ----------------
__global__ __launch_bounds__(256) void k_final(
    const float* __restrict__ x, const float* __restrict__ gate,
    float* __restrict__ out)
{
    const int idx = blockIdx.x * 256 + threadIdx.x;   // float4 index
    const int e = idx << 2;
    const int b = e >> 20;
    const int c = (e >> 12) & 255;
    const float g = gate[b * 256 + c];
    float4 xv = *(const float4*)(x + e);
    float4 ov = *(const float4*)(out + e);
    float4 rres;
    rres.x = fmaf(g, ov.x, xv.x);
    rres.y = fmaf(g, ov.y, xv.y);
    rres.z = fmaf(g, ov.z, xv.z);
    rres.w = fmaf(g, ov.w, xv.w);
    *(float4*)(out + e) = rres;
}

extern "C" void kernel_launch(void* const* d_in, const int* in_sizes, int n_in,
                              void* d_out, int out_size, void* d_ws, size_t ws_size,
                              hipStream_t stream)
{
    const float* x       = (const float*)d_in[0];
    const float* w_embed = (const float*)d_in[1];
    const float* b_embed = (const float*)d_in[2];
    const float* g1      = (const float*)d_in[3];
    const float* be1     = (const float*)d_in[4];
    const float* m1      = (const float*)d_in[5];
    const float* v1      = (const float*)d_in[6];
    const float* w_enh   = (const float*)d_in[7];
    const float* b_enh   = (const float*)d_in[8];
    const float* g2      = (const float*)d_in[9];
    const float* be2     = (const float*)d_in[10];
    const float* m2      = (const float*)d_in[11];
    const float* v2      = (const float*)d_in[12];
    const float* w_g1    = (const float*)d_in[13];
    const float* b_g1    = (const float*)d_in[14];
    const float* w_g2    = (const float*)d_in[15];
    const float* b_g2    = (const float*)d_in[16];
    float* ws  = (float*)d_ws;
    float* out = (float*)d_out;

    float* fe   = ws + OFS_FE;    // reused as agg after k_sim
    float* sim  = ws + OFS_SIM;
    float* wt1  = ws + OFS_WT1;
    float* bf1  = ws + OFS_B1;
    float* wt2  = ws + OFS_WT2;
    float* bf2  = ws + OFS_B2;
    float* pool = ws + OFS_POOL;
    float* gate = ws + OFS_GATE;

    k_prep<<<dim3(770), dim3(256), 0, stream>>>(
        w_embed, b_embed, g1, be1, m1, v1,
        w_enh, b_enh, g2, be2, m2, v2, ws);
    k_gemm<256><<<dim3(512), dim3(256), 0, stream>>>(x, x, wt1, bf1, fe);
    k_sim<<<dim3(512), dim3(256), 0, stream>>>(fe, sim);
    k_agg<<<dim3(512), dim3(256), 0, stream>>>(x, sim, fe);   // agg overwrites fe
    k_gemm<512><<<dim3(512), dim3(256), 0, stream>>>(x, fe, wt2, bf2, out); // enhanced -> d_out
    k_pool<<<dim3(1024), dim3(256), 0, stream>>>(x, out, pool);
    k_mlp<<<dim3(8), dim3(64), 0, stream>>>(pool, w_g1, b_g1, w_g2, b_g2, gate);
    k_final<<<dim3(8192), dim3(256), 0, stream>>>(x, gate, out);
}

// Round 2
// 309.981 us; speedup vs baseline: 1.4266x; 1.4266x over previous
//
#include <hip/hip_runtime.h>
#include <math.h>

typedef unsigned short u16;
typedef unsigned int   u32;
typedef __attribute__((ext_vector_type(8))) short short8;
typedef __attribute__((ext_vector_type(4))) float f32x4;

#define HW 4096

// ws layout (float offsets). Total ~35.15 MB (<= R1's 35.5 MB footprint).
#define OFS_XB   0ul          // 32768 x 512 bf16 (u16): [pixel][ch] ; ch 0-255 = x, 256-511 = agg
#define OFS_SIM  8388608ul    // 8*9*4096 fp32
#define OFS_W1B  8683520ul    // 256x256 bf16 folded embed weights [o][k]
#define OFS_W2B  8716288ul    // 256x512 bf16 folded enhance weights [o][k]
#define OFS_B1   8781824ul    // 256 fp32
#define OFS_B2   8782080ul    // 256 fp32
#define OFS_POOL 8782336ul    // 8*512
#define OFS_GATE 8786432ul    // 8*256

__device__ __forceinline__ u16 f2bf(float x) {
    union { float f; u32 u; } v; v.f = x;
    u32 r = v.u + 0x7fffu + ((v.u >> 16) & 1u);
    return (u16)(r >> 16);
}
__device__ __forceinline__ float bf2f(u16 h) {
    union { u32 u; float f; } v; v.u = ((u32)h) << 16;
    return v.f;
}
__device__ __forceinline__ void ld_g2l_16(u16* l, const u16* g) {
    __builtin_amdgcn_global_load_lds(
        (const __attribute__((address_space(1))) u32*)g,
        (__attribute__((address_space(3))) u32*)l,
        16, 0, 0);
}

// ---------------- prep: fold BN into bf16 weights ----------------
__global__ __launch_bounds__(256) void k_prep(
    const float* __restrict__ w1, const float* __restrict__ b1,
    const float* __restrict__ g1, const float* __restrict__ be1,
    const float* __restrict__ m1, const float* __restrict__ v1,
    const float* __restrict__ w2, const float* __restrict__ b2,
    const float* __restrict__ g2, const float* __restrict__ be2,
    const float* __restrict__ m2, const float* __restrict__ v2,
    u16* __restrict__ w1b, u16* __restrict__ w2b,
    float* __restrict__ b1f, float* __restrict__ b2f)
{
    int idx = blockIdx.x * 256 + threadIdx.x;
    if (idx < 65536) {                       // w1b[o][c], idx = o*256+c
        int o = idx >> 8;
        float inv = g1[o] * rsqrtf(v1[o] + 1e-5f);
        w1b[idx] = f2bf(w1[idx] * inv);
    } else if (idx < 196608) {               // w2b[o][k], j = o*512+k
        int j = idx - 65536;
        int o = j >> 9;
        float inv = g2[o] * rsqrtf(v2[o] + 1e-5f);
        w2b[j] = f2bf(w2[j] * inv);
    } else if (idx < 196864) {
        int o = idx - 196608;
        float inv = g1[o] * rsqrtf(v1[o] + 1e-5f);
        b1f[o] = b1[o] * inv + be1[o] - m1[o] * inv;
    } else if (idx < 197120) {
        int o = idx - 196864;
        float inv = g2[o] * rsqrtf(v2[o] + 1e-5f);
        b2f[o] = b2[o] * inv + be2[o] - m2[o] * inv;
    }
}

// ---------------- transpose+convert: x[b][c][p] fp32 -> xb[p][c] bf16 ----------------
__global__ __launch_bounds__(256) void k_cvt(
    const float* __restrict__ x, u16* __restrict__ xb)
{
    __shared__ float tile[64][65];
    const int t = threadIdx.x;
    const int id = blockIdx.x;
    const int pt = id & 63, ct = (id >> 6) & 3, b = id >> 8;
    const float* src = x + (((size_t)(b * 256 + ct * 64)) << 12) + pt * 64;
#pragma unroll
    for (int i = 0; i < 16; ++i) {
        int idx = i * 256 + t;
        int cl = idx >> 6, pl = idx & 63;
        tile[cl][pl] = src[((size_t)cl << 12) + pl];
    }
    __syncthreads();
#pragma unroll
    for (int i = 0; i < 8; ++i) {
        int idx = i * 256 + t;           // 0..2047
        int pl = idx >> 5, c2 = idx & 31;
        int cl = c2 * 2;
        u32 lo = f2bf(tile[cl][pl]);
        u32 hi = f2bf(tile[cl + 1][pl]);
        u32 pv = lo | (hi << 16);
        *(u32*)(xb + (((size_t)(b * 4096 + pt * 64 + pl)) << 9) + ct * 64 + cl) = pv;
    }
}

// ---------------- bf16 MFMA GEMM: out = relu(W @ X + bias) ----------------
// Block tile 128o x 128p, 4 waves (each 64o x 64p), K-chunks of 32.
// LDS holds 16x32 frag blocks as linear 1KB runs: conflict-free ds_read_b128
// at base+lane*16, and global_load_lds staging writes exactly base+lane*16.
template<int KIN, bool OUTBF>
__global__ __launch_bounds__(256) void k_gemm(
    const u16* __restrict__ xb, const u16* __restrict__ Wb,
    const float* __restrict__ biasf, void* __restrict__ outp)
{
    __shared__ __align__(16) u16 Wl[4096];
    __shared__ __align__(16) u16 Xl[4096];
    __shared__ float sbias[128];
    const int t = threadIdx.x;
    const int lane = t & 63;
    const int wv = t >> 6;
    const int p_blk = blockIdx.x * 128;
    const int o_blk = blockIdx.y * 128;
    const int owg = (wv & 1) * 4;      // o 16-row-group base
    const int pwg = (wv >> 1) * 4;     // p 16-row-group base
    const int r16 = lane & 15, q = lane >> 4;
    if (t < 128) sbias[t] = biasf[o_blk + t];

    f32x4 acc[4][4];
#pragma unroll
    for (int i = 0; i < 4; ++i)
#pragma unroll
        for (int j = 0; j < 4; ++j) acc[i][j] = (f32x4){0.f, 0.f, 0.f, 0.f};

    for (int kc = 0; kc < KIN / 32; ++kc) {
        const int kk = kc * 32 + q * 8;
#pragma unroll
        for (int s = 0; s < 4; ++s) {
            const int bi = wv * 4 + s;
            const u16* g;
            u16* l;
            if (bi < 8) {
                g = Wb + (size_t)(o_blk + bi * 16 + r16) * KIN + kk;
                l = Wl + bi * 512;
            } else {
                g = xb + (((size_t)(p_blk + (bi - 8) * 16 + r16)) << 9) + kk;
                l = Xl + (bi - 8) * 512;
            }
            ld_g2l_16(l, g);
        }
        __syncthreads();
        short8 af[4], bf[4];
#pragma unroll
        for (int i = 0; i < 4; ++i) af[i] = *(const short8*)(Wl + (owg + i) * 512 + lane * 8);
#pragma unroll
        for (int j = 0; j < 4; ++j) bf[j] = *(const short8*)(Xl + (pwg + j) * 512 + lane * 8);
#pragma unroll
        for (int i = 0; i < 4; ++i)
#pragma unroll
            for (int j = 0; j < 4; ++j)
                acc[i][j] = __builtin_amdgcn_mfma_f32_16x16x32_bf16(af[i], bf[j], acc[i][j], 0, 0, 0);
        __syncthreads();
    }

    // epilogue: D[row=o] = quad*4+reg, D[col=p] = lane&15  (m89-verified layout)
    float bia[4][4];
#pragma unroll
    for (int i = 0; i < 4; ++i)
#pragma unroll
        for (int r = 0; r < 4; ++r) bia[i][r] = sbias[owg * 16 + i * 16 + q * 4 + r];
    const int bidx = p_blk >> 12;
    const int pin0 = (p_blk & 4095) + pwg * 16 + r16;
#pragma unroll
    for (int i = 0; i < 4; ++i) {
#pragma unroll
        for (int r = 0; r < 4; ++r) {
            const int o = o_blk + owg * 16 + i * 16 + q * 4 + r;
            const size_t rowb = ((size_t)(bidx * 256 + o)) << 12;
#pragma unroll
            for (int j = 0; j < 4; ++j) {
                float v = fmaxf(acc[i][j][r] + bia[i][r], 0.f);
                const size_t oi = rowb + pin0 + j * 16;
                if (OUTBF) ((u16*)outp)[oi] = f2bf(v);
                else       ((float*)outp)[oi] = v;
            }
        }
    }
}

// ---------------- region cosine similarity + softmax (fe in bf16) ----------------
__global__ __launch_bounds__(256) void k_sim(
    const u16* __restrict__ fe, float* __restrict__ sim)
{
    __shared__ float red[4][64][18];
    const int t = threadIdx.x;
    const int w = t & 63, sl = t >> 6;
    const int r = blockIdx.x;
    const int b = r >> 6, h = r & 63;

    const int hh[3] = {h > 0 ? h - 1 : 0, h, h < 63 ? h + 1 : 63};
    const float mh[3] = {h > 0 ? 1.f : 0.f, 1.f, h < 63 ? 1.f : 0.f};
    const int wcl[3] = {w > 0 ? w - 1 : 0, w, w < 63 ? w + 1 : 63};
    const float mwv[3] = {w > 0 ? 1.f : 0.f, 1.f, w < 63 ? 1.f : 0.f};
    int offs[9];
    float msk[9];
#pragma unroll
    for (int i = 0; i < 3; ++i)
#pragma unroll
        for (int j = 0; j < 3; ++j) {
            offs[i * 3 + j] = hh[i] * 64 + wcl[j];
            msk[i * 3 + j] = mh[i] * mwv[j];
        }

    const u16* base = fe + (((size_t)(b * 256 + sl * 64)) << 12);
    float dot[9] = {};
    float np[9] = {};
#pragma unroll 4
    for (int ci = 0; ci < 64; ++ci) {
        const u16* p = base + ((size_t)ci << 12);
        float v[9];
#pragma unroll
        for (int k = 0; k < 9; ++k) v[k] = bf2f(p[offs[k]]) * msk[k];
        const float c0 = v[4];
#pragma unroll
        for (int k = 0; k < 9; ++k) {
            dot[k] = fmaf(c0, v[k], dot[k]);
            np[k] = fmaf(v[k], v[k], np[k]);
        }
    }
#pragma unroll
    for (int k = 0; k < 9; ++k) {
        red[sl][w][k] = dot[k];
        red[sl][w][9 + k] = np[k];
    }
    __syncthreads();
    if (t < 64) {
        float d[9], n[9];
#pragma unroll
        for (int k = 0; k < 9; ++k) {
            d[k] = red[0][w][k] + red[1][w][k] + red[2][w][k] + red[3][w][k];
            n[k] = red[0][w][9 + k] + red[1][w][9 + k] + red[2][w][9 + k] + red[3][w][9 + k];
        }
        const float nc = sqrtf(n[4]);
        float s[9];
#pragma unroll
        for (int k = 0; k < 9; ++k) s[k] = d[k] / (nc * sqrtf(n[k]) + 1e-7f);
        float mx = s[0];
#pragma unroll
        for (int k = 1; k < 9; ++k) mx = fmaxf(mx, s[k]);
        float e[9], sum = 0.f;
#pragma unroll
        for (int k = 0; k < 9; ++k) { e[k] = expf(s[k] - mx); sum += e[k]; }
        const float rs = 1.f / sum;
#pragma unroll
        for (int k = 0; k < 9; ++k)
            sim[(size_t)(b * 9 + k) * HW + h * 64 + w] = e[k] * rs;
    }
}

// ---------------- aggregation on x; writes bf16 into xb[:,256:512] ----------------
__global__ __launch_bounds__(256) void k_agg(
    const float* __restrict__ x, const float* __restrict__ sim,
    u16* __restrict__ xb)
{
    __shared__ float simbuf[9][64];
    const int t = threadIdx.x;
    const int r = blockIdx.x;
    const int b = r >> 6, h = r & 63;
    for (int i = t; i < 576; i += 256) {
        int k = i >> 6, ww = i & 63;
        simbuf[k][ww] = sim[(size_t)(b * 9 + k) * HW + h * 64 + ww];
    }
    __syncthreads();
    const int w = t & 63, cg = t >> 6;
    const int hh[3] = {h > 0 ? h - 1 : 0, h, h < 63 ? h + 1 : 63};
    const float mh[3] = {h > 0 ? 1.f : 0.f, 1.f, h < 63 ? 1.f : 0.f};
    const int wcl[3] = {w > 0 ? w - 1 : 0, w, w < 63 ? w + 1 : 63};
    const float mwv[3] = {w > 0 ? 1.f : 0.f, 1.f, w < 63 ? 1.f : 0.f};
    int offs[9];
    float ms[9];
#pragma unroll
    for (int i = 0; i < 3; ++i)
#pragma unroll
        for (int j = 0; j < 3; ++j) {
            offs[i * 3 + j] = hh[i] * 64 + wcl[j];
            ms[i * 3 + j] = mh[i] * mwv[j] * simbuf[i * 3 + j][w];
        }
    u16* orow = xb + (((size_t)(b * 4096 + h * 64 + w)) << 9) + 256 + cg * 64;
    for (int cc = 0; cc < 8; ++cc) {
        union { u16 a[8]; short8 v; } pk;
#pragma unroll
        for (int u = 0; u < 8; ++u) {
            const int c = cg * 64 + cc * 8 + u;
            const float* p = x + (((size_t)(b * 256 + c)) << 12);
            float s = 0.f;
#pragma unroll
            for (int k = 0; k < 9; ++k) s = fmaf(p[offs[k]], ms[k], s);
            pk.a[u] = f2bf(s);
        }
        *(short8*)(orow + cc * 8) = pk.v;
    }
}

// ---------------- global average pool of concat([x, enhanced]) ----------------
__global__ __launch_bounds__(256) void k_pool(
    const float* __restrict__ x, const float* __restrict__ enh,
    float* __restrict__ pool)
{
    const int t = threadIdx.x;
    const int g = blockIdx.x * 4 + (t >> 6);
    const int lane = t & 63;
    const int b = g >> 9, j = g & 511;
    const float* src = (j < 256) ? x + (size_t)(b * 256 + j) * HW
                                 : enh + (size_t)(b * 256 + j - 256) * HW;
    float s = 0.f;
    for (int i = 0; i < 64; ++i) s += src[lane + i * 64];
    for (int off = 32; off > 0; off >>= 1) s += __shfl_down(s, off, 64);
    if (lane == 0) pool[g] = s * (1.f / 4096.f);
}

// ---------------- SE-style gate MLP ----------------
__global__ __launch_bounds__(64) void k_mlp(
    const float* __restrict__ pool,
    const float* __restrict__ wg1, const float* __restrict__ bg1,
    const float* __restrict__ wg2, const float* __restrict__ bg2,
    float* __restrict__ gate)
{
    __shared__ float pl[512];
    __shared__ float hb[64];
    const int b = blockIdx.x, t = threadIdx.x;
    for (int i = t; i < 512; i += 64) pl[i] = pool[b * 512 + i];
    __syncthreads();
    float s = bg1[t];
    const float* wr = wg1 + t * 512;
    for (int c = 0; c < 512; ++c) s = fmaf(wr[c], pl[c], s);
    hb[t] = fmaxf(s, 0.f);
    __syncthreads();
#pragma unroll
    for (int rr = 0; rr < 4; ++rr) {
        const int o = t + rr * 64;
        float s2 = bg2[o];
        const float* w2 = wg2 + o * 64;
        for (int j = 0; j < 64; ++j) s2 = fmaf(w2[j], hb[j], s2);
        gate[b * 256 + o] = 1.f / (1.f + expf(-s2));
    }
}

// ---------------- final: out = x + gate * enhanced (in-place) ----------------
__global__ __launch_bounds__(256) void k_final(
    const float* __restrict__ x, const float* __restrict__ gate,
    float* __restrict__ out)
{
    const int idx = blockIdx.x * 256 + threadIdx.x;
    const int e = idx << 2;
    const int b = e >> 20;
    const int c = (e >> 12) & 255;
    const float g = gate[b * 256 + c];
    float4 xv = *(const float4*)(x + e);
    float4 ov = *(const float4*)(out + e);
    float4 rres;
    rres.x = fmaf(g, ov.x, xv.x);
    rres.y = fmaf(g, ov.y, xv.y);
    rres.z = fmaf(g, ov.z, xv.z);
    rres.w = fmaf(g, ov.w, xv.w);
    *(float4*)(out + e) = rres;
}

extern "C" void kernel_launch(void* const* d_in, const int* in_sizes, int n_in,
                              void* d_out, int out_size, void* d_ws, size_t ws_size,
                              hipStream_t stream)
{
    const float* x       = (const float*)d_in[0];
    const float* w_embed = (const float*)d_in[1];
    const float* b_embed = (const float*)d_in[2];
    const float* g1      = (const float*)d_in[3];
    const float* be1     = (const float*)d_in[4];
    const float* m1      = (const float*)d_in[5];
    const float* v1      = (const float*)d_in[6];
    const float* w_enh   = (const float*)d_in[7];
    const float* b_enh   = (const float*)d_in[8];
    const float* g2      = (const float*)d_in[9];
    const float* be2     = (const float*)d_in[10];
    const float* m2      = (const float*)d_in[11];
    const float* v2      = (const float*)d_in[12];
    const float* w_g1    = (const float*)d_in[13];
    const float* b_g1    = (const float*)d_in[14];
    const float* w_g2    = (const float*)d_in[15];
    const float* b_g2    = (const float*)d_in[16];
    float* ws  = (float*)d_ws;
    float* out = (float*)d_out;

    u16*   xb   = (u16*)(ws + OFS_XB);
    float* sim  = ws + OFS_SIM;
    u16*   w1b  = (u16*)(ws + OFS_W1B);
    u16*   w2b  = (u16*)(ws + OFS_W2B);
    float* b1f  = ws + OFS_B1;
    float* b2f  = ws + OFS_B2;
    float* pool = ws + OFS_POOL;
    float* gate = ws + OFS_GATE;
    u16*   fe   = (u16*)d_out;   // fe (bf16) lives in d_out; dead before gemm2 overwrites

    k_prep<<<dim3(770), dim3(256), 0, stream>>>(
        w_embed, b_embed, g1, be1, m1, v1,
        w_enh, b_enh, g2, be2, m2, v2, w1b, w2b, b1f, b2f);
    k_cvt<<<dim3(2048), dim3(256), 0, stream>>>(x, xb);
    k_gemm<256, true><<<dim3(256, 2), dim3(256), 0, stream>>>(xb, w1b, b1f, (void*)fe);
    k_sim<<<dim3(512), dim3(256), 0, stream>>>(fe, sim);
    k_agg<<<dim3(512), dim3(256), 0, stream>>>(x, sim, xb);
    k_gemm<512, false><<<dim3(256, 2), dim3(256), 0, stream>>>(xb, w2b, b2f, (void*)out);
    k_pool<<<dim3(1024), dim3(256), 0, stream>>>(x, out, pool);
    k_mlp<<<dim3(8), dim3(64), 0, stream>>>(pool, w_g1, b_g1, w_g2, b_g2, gate);
    k_final<<<dim3(8192), dim3(256), 0, stream>>>(x, gate, out);
}

// Round 4
// 227.480 us; speedup vs baseline: 1.9440x; 1.3627x over previous
//
#include <hip/hip_runtime.h>
#include <math.h>

typedef unsigned short u16;
typedef unsigned int   u32;
typedef __attribute__((ext_vector_type(8))) short short8;
typedef __attribute__((ext_vector_type(4))) float f32x4;

#define HW 4096

// ws layout (float offsets). Total ~35.15 MB (proven in R1/R2).
#define OFS_XB   0ul          // 32768 x 512 bf16 (u16): [pixel][ch] ; ch 0-255 = x, 256-511 = agg
#define OFS_PD   8388608ul    // 8*9*4096 fp32 partial dot sums (atomic-accumulated)
#define OFS_W1B  8683520ul    // 256x256 bf16 folded embed weights [o][k]
#define OFS_W2B  8716288ul    // 256x512 bf16 folded enhance weights [o][k]
#define OFS_B1   8781824ul    // 256 fp32
#define OFS_B2   8782080ul    // 256 fp32
#define OFS_POOL 8782336ul    // 8*512
#define OFS_GATE 8786432ul    // 8*256

__device__ __forceinline__ u16 f2bf(float x) {
    union { float f; u32 u; } v; v.f = x;
    u32 r = v.u + 0x7fffu + ((v.u >> 16) & 1u);
    return (u16)(r >> 16);
}
__device__ __forceinline__ float bf2f(u16 h) {
    union { u32 u; float f; } v; v.u = ((u32)h) << 16;
    return v.f;
}
__device__ __forceinline__ void ld_g2l_16(u16* l, const u16* g) {
    __builtin_amdgcn_global_load_lds(
        (const __attribute__((address_space(1))) u32*)g,
        (__attribute__((address_space(3))) u32*)l,
        16, 0, 0);
}

// ---------------- prep: fold BN into bf16 weights ----------------
__global__ __launch_bounds__(256) void k_prep(
    const float* __restrict__ w1, const float* __restrict__ b1,
    const float* __restrict__ g1, const float* __restrict__ be1,
    const float* __restrict__ m1, const float* __restrict__ v1,
    const float* __restrict__ w2, const float* __restrict__ b2,
    const float* __restrict__ g2, const float* __restrict__ be2,
    const float* __restrict__ m2, const float* __restrict__ v2,
    u16* __restrict__ w1b, u16* __restrict__ w2b,
    float* __restrict__ b1f, float* __restrict__ b2f)
{
    int idx = blockIdx.x * 256 + threadIdx.x;
    if (idx < 65536) {                       // w1b[o][c], idx = o*256+c
        int o = idx >> 8;
        float inv = g1[o] * rsqrtf(v1[o] + 1e-5f);
        w1b[idx] = f2bf(w1[idx] * inv);
    } else if (idx < 196608) {               // w2b[o][k], j = o*512+k
        int j = idx - 65536;
        int o = j >> 9;
        float inv = g2[o] * rsqrtf(v2[o] + 1e-5f);
        w2b[j] = f2bf(w2[j] * inv);
    } else if (idx < 196864) {
        int o = idx - 196608;
        float inv = g1[o] * rsqrtf(v1[o] + 1e-5f);
        b1f[o] = b1[o] * inv + be1[o] - m1[o] * inv;
    } else if (idx < 197120) {
        int o = idx - 196864;
        float inv = g2[o] * rsqrtf(v2[o] + 1e-5f);
        b2f[o] = b2[o] * inv + be2[o] - m2[o] * inv;
    }
}

// ---------------- transpose+convert: x[b][c][p] fp32 -> xb[p][c] bf16 ----------------
__global__ __launch_bounds__(256) void k_cvt(
    const float* __restrict__ x, u16* __restrict__ xb)
{
    __shared__ float tile[64][65];
    const int t = threadIdx.x;
    const int id = blockIdx.x;
    const int pt = id & 63, ct = (id >> 6) & 3, b = id >> 8;
    const float* src = x + (((size_t)(b * 256 + ct * 64)) << 12) + pt * 64;
#pragma unroll
    for (int i = 0; i < 16; ++i) {
        int idx = i * 256 + t;
        int cl = idx >> 6, pl = idx & 63;
        tile[cl][pl] = src[((size_t)cl << 12) + pl];
    }
    __syncthreads();
#pragma unroll
    for (int i = 0; i < 8; ++i) {
        int idx = i * 256 + t;           // 0..2047
        int pl = idx >> 5, c2 = idx & 31;
        int cl = c2 * 2;
        u32 lo = f2bf(tile[cl][pl]);
        u32 hi = f2bf(tile[cl + 1][pl]);
        u32 pv = lo | (hi << 16);
        *(u32*)(xb + (((size_t)(b * 4096 + pt * 64 + pl)) << 9) + ct * 64 + cl) = pv;
    }
}

// ---------------- bf16 MFMA GEMM: out = relu(W @ X + bias) ----------------
template<int KIN, bool OUTBF>
__global__ __launch_bounds__(256) void k_gemm(
    const u16* __restrict__ xb, const u16* __restrict__ Wb,
    const float* __restrict__ biasf, void* __restrict__ outp)
{
    __shared__ __align__(16) u16 Wl[4096];
    __shared__ __align__(16) u16 Xl[4096];
    __shared__ float sbias[128];
    const int t = threadIdx.x;
    const int lane = t & 63;
    const int wv = t >> 6;
    const int p_blk = blockIdx.x * 128;
    const int o_blk = blockIdx.y * 128;
    const int owg = (wv & 1) * 4;
    const int pwg = (wv >> 1) * 4;
    const int r16 = lane & 15, q = lane >> 4;
    if (t < 128) sbias[t] = biasf[o_blk + t];

    f32x4 acc[4][4];
#pragma unroll
    for (int i = 0; i < 4; ++i)
#pragma unroll
        for (int j = 0; j < 4; ++j) acc[i][j] = (f32x4){0.f, 0.f, 0.f, 0.f};

    for (int kc = 0; kc < KIN / 32; ++kc) {
        const int kk = kc * 32 + q * 8;
#pragma unroll
        for (int s = 0; s < 4; ++s) {
            const int bi = wv * 4 + s;
            const u16* g;
            u16* l;
            if (bi < 8) {
                g = Wb + (size_t)(o_blk + bi * 16 + r16) * KIN + kk;
                l = Wl + bi * 512;
            } else {
                g = xb + (((size_t)(p_blk + (bi - 8) * 16 + r16)) << 9) + kk;
                l = Xl + (bi - 8) * 512;
            }
            ld_g2l_16(l, g);
        }
        __syncthreads();
        short8 af[4], bf[4];
#pragma unroll
        for (int i = 0; i < 4; ++i) af[i] = *(const short8*)(Wl + (owg + i) * 512 + lane * 8);
#pragma unroll
        for (int j = 0; j < 4; ++j) bf[j] = *(const short8*)(Xl + (pwg + j) * 512 + lane * 8);
#pragma unroll
        for (int i = 0; i < 4; ++i)
#pragma unroll
            for (int j = 0; j < 4; ++j)
                acc[i][j] = __builtin_amdgcn_mfma_f32_16x16x32_bf16(af[i], bf[j], acc[i][j], 0, 0, 0);
        __syncthreads();
    }

    float bia[4][4];
#pragma unroll
    for (int i = 0; i < 4; ++i)
#pragma unroll
        for (int r = 0; r < 4; ++r) bia[i][r] = sbias[owg * 16 + i * 16 + q * 4 + r];
    const int bidx = p_blk >> 12;
    const int pin0 = (p_blk & 4095) + pwg * 16 + r16;
#pragma unroll
    for (int i = 0; i < 4; ++i) {
#pragma unroll
        for (int r = 0; r < 4; ++r) {
            const int o = o_blk + owg * 16 + i * 16 + q * 4 + r;
            const size_t rowb = ((size_t)(bidx * 256 + o)) << 12;
#pragma unroll
            for (int j = 0; j < 4; ++j) {
                float v = fmaxf(acc[i][j][r] + bia[i][r], 0.f);
                const size_t oi = rowb + pin0 + j * 16;
                if (OUTBF) ((u16*)outp)[oi] = f2bf(v);
                else       ((float*)outp)[oi] = v;
            }
        }
    }
}

// ---------------- region dot products (partial over 64-ch group) ----------------
// np is NOT computed: n_k(p) = dot4(p+off_k) (center-norm plane, k=4).
__global__ __launch_bounds__(256) void k_sim(
    const u16* __restrict__ fe, float* __restrict__ pd)
{
    __shared__ __align__(16) u16 st[3 * 4096];   // [r][c][px]
    __shared__ float red[4][64][9];
    const int t = threadIdx.x;
    const int id = blockIdx.x;
    const int g = id & 3, h = (id >> 2) & 63, b = id >> 8;
    const int rows[3] = {h > 0 ? h - 1 : 0, h, h < 63 ? h + 1 : 63};
    const u16* base = fe + (((size_t)(b * 256 + g * 64)) << 12);
#pragma unroll
    for (int it = 0; it < 6; ++it) {
        const int flat = it * 256 + t;
        const int r = flat >> 9, j = flat & 511;     // j = c*8 + chunk
        const u16* gs = base + ((size_t)(j >> 3) << 12) + rows[r] * 64 + (j & 7) * 8;
        ld_g2l_16(st + r * 4096 + j * 8, gs);
    }
    __syncthreads();
    const int w = t & 63, sl = t >> 6;
    const int wl = w > 0 ? w - 1 : 0, wr = w < 63 ? w + 1 : 63;
    float dot[9] = {};
    const u16* s0 = st + sl * 16 * 64;
#pragma unroll 4
    for (int ci = 0; ci < 16; ++ci) {
        const u16* pc = s0 + ci * 64;
        float v[9];
#pragma unroll
        for (int r = 0; r < 3; ++r) {
            v[r * 3 + 0] = bf2f(pc[r * 4096 + wl]);
            v[r * 3 + 1] = bf2f(pc[r * 4096 + w]);
            v[r * 3 + 2] = bf2f(pc[r * 4096 + wr]);
        }
        const float c0 = v[4];
#pragma unroll
        for (int k = 0; k < 9; ++k) dot[k] = fmaf(c0, v[k], dot[k]);
    }
#pragma unroll
    for (int k = 0; k < 9; ++k) red[sl][w][k] = dot[k];
    __syncthreads();
    if (t < 64) {
        const int p = h * 64 + w;
#pragma unroll
        for (int k = 0; k < 9; ++k) {
            float s = red[0][w][k] + red[1][w][k] + red[2][w][k] + red[3][w][k];
            atomicAdd(&pd[((size_t)(b * 9 + k) << 12) + p], s);
        }
    }
}

// ---------------- softmax (fused) + aggregation; writes bf16 into xb[:,256:512] ----------------
// FIX vs R3: stored weight = border_mask * softmax (softmax denom still over
// all 9 entries, matching the reference where OOB terms have xpats==0).
__global__ __launch_bounds__(256) void k_agg(
    const u16* __restrict__ xb, const float* __restrict__ pd,
    u16* __restrict__ xbo)
{
    __shared__ __align__(16) u16 xt[3 * 4096];   // [r][px][c]
    __shared__ float ws9[9][64];
    const int t = threadIdx.x;
    const int id = blockIdx.x;
    const int g = id & 3, h = (id >> 2) & 63, b = id >> 8;
    const int rows[3] = {h > 0 ? h - 1 : 0, h, h < 63 ? h + 1 : 63};
    const u16* base = xb + (((size_t)(b * 4096)) << 9) + g * 64;
#pragma unroll
    for (int it = 0; it < 6; ++it) {
        const int flat = it * 256 + t;
        const int r = flat >> 9, j = flat & 511;     // j = px*8 + chunk
        const u16* gs = base + (((size_t)(rows[r] * 64 + (j >> 3))) << 9) + (j & 7) * 8;
        ld_g2l_16(xt + r * 4096 + j * 8, gs);
    }
    if (t < 64) {
        const int w = t;
        const int p = h * 64 + w;
        const float* pb = pd + (((size_t)(b * 9)) << 12);
        const float nc = sqrtf(pb[(4 << 12) + p]);
        float s[9], mk[9];
#pragma unroll
        for (int di = -1; di <= 1; ++di)
#pragma unroll
            for (int dj = -1; dj <= 1; ++dj) {
                const int k = (di + 1) * 3 + (dj + 1);
                const int hn = h + di, wn = w + dj;
                const float mask = (hn >= 0 && hn < 64 && wn >= 0 && wn < 64) ? 1.f : 0.f;
                const int hc = hn < 0 ? 0 : (hn > 63 ? 63 : hn);
                const int wc = wn < 0 ? 0 : (wn > 63 ? 63 : wn);
                const float nk = pb[(4 << 12) + hc * 64 + wc];
                const float dk = pb[(k << 12) + p];
                mk[k] = mask;
                s[k] = mask * dk / (nc * sqrtf(nk) + 1e-7f);
            }
        float mx = s[0];
#pragma unroll
        for (int k = 1; k < 9; ++k) mx = fmaxf(mx, s[k]);
        float e[9], sum = 0.f;
#pragma unroll
        for (int k = 0; k < 9; ++k) { e[k] = expf(s[k] - mx); sum += e[k]; }
        const float rs = 1.f / sum;
#pragma unroll
        for (int k = 0; k < 9; ++k) ws9[k][w] = mk[k] * e[k] * rs;   // masked weight
    }
    __syncthreads();
    const int c = t & 63, pg = t >> 6;   // 16 px per thread, lane = channel
    u16* orow = xbo + (((size_t)(b * 4096 + h * 64)) << 9) + 256 + g * 64 + c;
#pragma unroll 4
    for (int pi = 0; pi < 16; ++pi) {
        const int px = pg * 16 + pi;
        const int pl = px > 0 ? px - 1 : 0, pr = px < 63 ? px + 1 : 63;
        const int pxs[3] = {pl, px, pr};
        float m[9];
#pragma unroll
        for (int k = 0; k < 9; ++k) m[k] = ws9[k][px];
        float acc = 0.f;
#pragma unroll
        for (int r = 0; r < 3; ++r)
#pragma unroll
            for (int j = 0; j < 3; ++j)
                acc = fmaf(bf2f(xt[r * 4096 + pxs[j] * 64 + c]), m[r * 3 + j], acc);
        orow[(size_t)px << 9] = f2bf(acc);
    }
}

// ---------------- global average pool of concat([x, enhanced]) ----------------
__global__ __launch_bounds__(256) void k_pool(
    const float* __restrict__ x, const float* __restrict__ enh,
    float* __restrict__ pool)
{
    const int t = threadIdx.x;
    const int g = blockIdx.x * 4 + (t >> 6);
    const int lane = t & 63;
    const int b = g >> 9, j = g & 511;
    const float* src = (j < 256) ? x + (size_t)(b * 256 + j) * HW
                                 : enh + (size_t)(b * 256 + j - 256) * HW;
    float s = 0.f;
    for (int i = 0; i < 64; ++i) s += src[lane + i * 64];
    for (int off = 32; off > 0; off >>= 1) s += __shfl_down(s, off, 64);
    if (lane == 0) pool[g] = s * (1.f / 4096.f);
}

// ---------------- SE-style gate MLP ----------------
__global__ __launch_bounds__(64) void k_mlp(
    const float* __restrict__ pool,
    const float* __restrict__ wg1, const float* __restrict__ bg1,
    const float* __restrict__ wg2, const float* __restrict__ bg2,
    float* __restrict__ gate)
{
    __shared__ float pl[512];
    __shared__ float hb[64];
    const int b = blockIdx.x, t = threadIdx.x;
    for (int i = t; i < 512; i += 64) pl[i] = pool[b * 512 + i];
    __syncthreads();
    float s = bg1[t];
    const float* wr = wg1 + t * 512;
    for (int c = 0; c < 512; ++c) s = fmaf(wr[c], pl[c], s);
    hb[t] = fmaxf(s, 0.f);
    __syncthreads();
#pragma unroll
    for (int rr = 0; rr < 4; ++rr) {
        const int o = t + rr * 64;
        float s2 = bg2[o];
        const float* w2 = wg2 + o * 64;
        for (int j = 0; j < 64; ++j) s2 = fmaf(w2[j], hb[j], s2);
        gate[b * 256 + o] = 1.f / (1.f + expf(-s2));
    }
}

// ---------------- final: out = x + gate * enhanced (in-place) ----------------
__global__ __launch_bounds__(256) void k_final(
    const float* __restrict__ x, const float* __restrict__ gate,
    float* __restrict__ out)
{
    const int idx = blockIdx.x * 256 + threadIdx.x;
    const int e = idx << 2;
    const int b = e >> 20;
    const int c = (e >> 12) & 255;
    const float g = gate[b * 256 + c];
    float4 xv = *(const float4*)(x + e);
    float4 ov = *(const float4*)(out + e);
    float4 rres;
    rres.x = fmaf(g, ov.x, xv.x);
    rres.y = fmaf(g, ov.y, xv.y);
    rres.z = fmaf(g, ov.z, xv.z);
    rres.w = fmaf(g, ov.w, xv.w);
    *(float4*)(out + e) = rres;
}

extern "C" void kernel_launch(void* const* d_in, const int* in_sizes, int n_in,
                              void* d_out, int out_size, void* d_ws, size_t ws_size,
                              hipStream_t stream)
{
    const float* x       = (const float*)d_in[0];
    const float* w_embed = (const float*)d_in[1];
    const float* b_embed = (const float*)d_in[2];
    const float* g1      = (const float*)d_in[3];
    const float* be1     = (const float*)d_in[4];
    const float* m1      = (const float*)d_in[5];
    const float* v1      = (const float*)d_in[6];
    const float* w_enh   = (const float*)d_in[7];
    const float* b_enh   = (const float*)d_in[8];
    const float* g2      = (const float*)d_in[9];
    const float* be2     = (const float*)d_in[10];
    const float* m2      = (const float*)d_in[11];
    const float* v2      = (const float*)d_in[12];
    const float* w_g1    = (const float*)d_in[13];
    const float* b_g1    = (const float*)d_in[14];
    const float* w_g2    = (const float*)d_in[15];
    const float* b_g2    = (const float*)d_in[16];
    float* ws  = (float*)d_ws;
    float* out = (float*)d_out;

    u16*   xb   = (u16*)(ws + OFS_XB);
    float* pd   = ws + OFS_PD;
    u16*   w1b  = (u16*)(ws + OFS_W1B);
    u16*   w2b  = (u16*)(ws + OFS_W2B);
    float* b1f  = ws + OFS_B1;
    float* b2f  = ws + OFS_B2;
    float* pool = ws + OFS_POOL;
    float* gate = ws + OFS_GATE;
    u16*   fe   = (u16*)d_out;   // fe (bf16) lives in d_out; dead before gemm2 overwrites

    hipMemsetAsync(pd, 0, (size_t)8 * 9 * 4096 * 4, stream);
    k_prep<<<dim3(770), dim3(256), 0, stream>>>(
        w_embed, b_embed, g1, be1, m1, v1,
        w_enh, b_enh, g2, be2, m2, v2, w1b, w2b, b1f, b2f);
    k_cvt<<<dim3(2048), dim3(256), 0, stream>>>(x, xb);
    k_gemm<256, true><<<dim3(256, 2), dim3(256), 0, stream>>>(xb, w1b, b1f, (void*)fe);
    k_sim<<<dim3(2048), dim3(256), 0, stream>>>(fe, pd);
    k_agg<<<dim3(2048), dim3(256), 0, stream>>>(xb, pd, xb);
    k_gemm<512, false><<<dim3(256, 2), dim3(256), 0, stream>>>(xb, w2b, b2f, (void*)out);
    k_pool<<<dim3(1024), dim3(256), 0, stream>>>(x, out, pool);
    k_mlp<<<dim3(8), dim3(64), 0, stream>>>(pool, w_g1, b_g1, w_g2, b_g2, gate);
    k_final<<<dim3(8192), dim3(256), 0, stream>>>(x, gate, out);
}

// Round 5
// 214.557 us; speedup vs baseline: 2.0611x; 1.0602x over previous
//
#include <hip/hip_runtime.h>
#include <math.h>

typedef unsigned short u16;
typedef unsigned int   u32;
typedef __attribute__((ext_vector_type(8))) short short8;
typedef __attribute__((ext_vector_type(4))) float f32x4;

#define HW 4096

// ws layout (float offsets). ws_size = 256 MiB (measured via harness poison fill).
#define OFS_XB   0ul          // 32768 x 512 bf16 (u16): [pixel][ch] ; ch 0-255 = x, 256-511 = agg
#define OFS_PD   8388608ul    // 8*9*4096 fp32 partial dot sums (atomic-accumulated)
#define OFS_W1B  8683520ul    // 256x256 bf16 folded embed weights [o][k]
#define OFS_W2B  8716288ul    // 256x512 bf16 folded enhance weights [o][k]
#define OFS_B1   8781824ul    // 256 fp32
#define OFS_B2   8782080ul    // 256 fp32
#define OFS_POOL 8782336ul    // 8*512 fp32 (atomic-accumulated means)
#define OFS_GATE 8786432ul    // 8*256
#define OFS_ENH  8788480ul    // 32768x256 bf16 enhanced (4.19M floats)

__device__ __forceinline__ u16 f2bf(float x) {
    union { float f; u32 u; } v; v.f = x;
    u32 r = v.u + 0x7fffu + ((v.u >> 16) & 1u);
    return (u16)(r >> 16);
}
__device__ __forceinline__ float bf2f(u16 h) {
    union { u32 u; float f; } v; v.u = ((u32)h) << 16;
    return v.f;
}
__device__ __forceinline__ void ld_g2l_16(u16* l, const u16* g) {
    __builtin_amdgcn_global_load_lds(
        (const __attribute__((address_space(1))) u32*)g,
        (__attribute__((address_space(3))) u32*)l,
        16, 0, 0);
}

// ---------------- prep: fold BN into bf16 weights + zero pd/pool ----------------
__global__ __launch_bounds__(256) void k_prep(
    const float* __restrict__ w1, const float* __restrict__ b1,
    const float* __restrict__ g1, const float* __restrict__ be1,
    const float* __restrict__ m1, const float* __restrict__ v1,
    const float* __restrict__ w2, const float* __restrict__ b2,
    const float* __restrict__ g2, const float* __restrict__ be2,
    const float* __restrict__ m2, const float* __restrict__ v2,
    u16* __restrict__ w1b, u16* __restrict__ w2b,
    float* __restrict__ b1f, float* __restrict__ b2f,
    float* __restrict__ pd, float* __restrict__ pool)
{
    const int bid = blockIdx.x, t = threadIdx.x;
    if (bid >= 770) {                        // zero pd (288 blocks) + pool (4 blocks)
        const int zid = bid - 770;
        const float4 z = {0.f, 0.f, 0.f, 0.f};
        if (zid < 288) ((float4*)(pd + zid * 1024))[t] = z;
        else           ((float4*)(pool + (zid - 288) * 1024))[t] = z;
        return;
    }
    int idx = bid * 256 + t;
    if (idx < 65536) {                       // w1b[o][c], idx = o*256+c
        int o = idx >> 8;
        float inv = g1[o] * rsqrtf(v1[o] + 1e-5f);
        w1b[idx] = f2bf(w1[idx] * inv);
    } else if (idx < 196608) {               // w2b[o][k], j = o*512+k
        int j = idx - 65536;
        int o = j >> 9;
        float inv = g2[o] * rsqrtf(v2[o] + 1e-5f);
        w2b[j] = f2bf(w2[j] * inv);
    } else if (idx < 196864) {
        int o = idx - 196608;
        float inv = g1[o] * rsqrtf(v1[o] + 1e-5f);
        b1f[o] = b1[o] * inv + be1[o] - m1[o] * inv;
    } else if (idx < 197120) {
        int o = idx - 196864;
        float inv = g2[o] * rsqrtf(v2[o] + 1e-5f);
        b2f[o] = b2[o] * inv + be2[o] - m2[o] * inv;
    }
}

// ---------------- transpose+convert x -> xb bf16, fused x-mean pool ----------------
__global__ __launch_bounds__(256) void k_cvt(
    const float* __restrict__ x, u16* __restrict__ xb, float* __restrict__ pool)
{
    __shared__ float tile[64][65];
    const int t = threadIdx.x;
    const int id = blockIdx.x;
    const int pt = id & 63, ct = (id >> 6) & 3, b = id >> 8;
    const float* src = x + (((size_t)(b * 256 + ct * 64)) << 12) + pt * 64;
#pragma unroll
    for (int i = 0; i < 16; ++i) {
        int idx = i * 256 + t;
        int cl = idx >> 6, pl = idx & 63;
        tile[cl][pl] = src[((size_t)cl << 12) + pl];
    }
    __syncthreads();
#pragma unroll
    for (int i = 0; i < 8; ++i) {
        int idx = i * 256 + t;           // 0..2047
        int pl = idx >> 5, c2 = idx & 31;
        int cl = c2 * 2;
        u32 lo = f2bf(tile[cl][pl]);
        u32 hi = f2bf(tile[cl + 1][pl]);
        u32 pv = lo | (hi << 16);
        *(u32*)(xb + (((size_t)(b * 4096 + pt * 64 + pl)) << 9) + ct * 64 + cl) = pv;
    }
    if (t < 64) {                        // x-half of the SE pool (f32, pre-rounding)
        float s = 0.f;
#pragma unroll
        for (int i = 0; i < 64; ++i) s += tile[t][i];
        atomicAdd(&pool[(b << 9) + ct * 64 + t], s * (1.f / 4096.f));
    }
}

// ---------------- bf16 MFMA GEMM: out = relu(W @ X + bias) [+ fused pool] ----------------
template<int KIN, bool OUTBF, bool DOPOOL>
__global__ __launch_bounds__(256) void k_gemm(
    const u16* __restrict__ xb, const u16* __restrict__ Wb,
    const float* __restrict__ biasf, void* __restrict__ outp,
    float* __restrict__ poolp)
{
    __shared__ __align__(16) u16 Wl[4096];
    __shared__ __align__(16) u16 Xl[4096];
    __shared__ float sbias[128];
    const int t = threadIdx.x;
    const int lane = t & 63;
    const int wv = t >> 6;
    const int p_blk = blockIdx.x * 128;
    const int o_blk = blockIdx.y * 128;
    const int owg = (wv & 1) * 4;
    const int pwg = (wv >> 1) * 4;
    const int r16 = lane & 15, q = lane >> 4;
    if (t < 128) sbias[t] = biasf[o_blk + t];

    f32x4 acc[4][4];
#pragma unroll
    for (int i = 0; i < 4; ++i)
#pragma unroll
        for (int j = 0; j < 4; ++j) acc[i][j] = (f32x4){0.f, 0.f, 0.f, 0.f};

    for (int kc = 0; kc < KIN / 32; ++kc) {
        const int kk = kc * 32 + q * 8;
#pragma unroll
        for (int s = 0; s < 4; ++s) {
            const int bi = wv * 4 + s;
            const u16* g;
            u16* l;
            if (bi < 8) {
                g = Wb + (size_t)(o_blk + bi * 16 + r16) * KIN + kk;
                l = Wl + bi * 512;
            } else {
                g = xb + (((size_t)(p_blk + (bi - 8) * 16 + r16)) << 9) + kk;
                l = Xl + (bi - 8) * 512;
            }
            ld_g2l_16(l, g);
        }
        __syncthreads();
        short8 af[4], bf[4];
#pragma unroll
        for (int i = 0; i < 4; ++i) af[i] = *(const short8*)(Wl + (owg + i) * 512 + lane * 8);
#pragma unroll
        for (int j = 0; j < 4; ++j) bf[j] = *(const short8*)(Xl + (pwg + j) * 512 + lane * 8);
#pragma unroll
        for (int i = 0; i < 4; ++i)
#pragma unroll
            for (int j = 0; j < 4; ++j)
                acc[i][j] = __builtin_amdgcn_mfma_f32_16x16x32_bf16(af[i], bf[j], acc[i][j], 0, 0, 0);
        __syncthreads();
    }

    float bia[4][4];
#pragma unroll
    for (int i = 0; i < 4; ++i)
#pragma unroll
        for (int r = 0; r < 4; ++r) bia[i][r] = sbias[owg * 16 + i * 16 + q * 4 + r];
    const int bidx = p_blk >> 12;
    const int pin0 = (p_blk & 4095) + pwg * 16 + r16;
#pragma unroll
    for (int i = 0; i < 4; ++i) {
#pragma unroll
        for (int r = 0; r < 4; ++r) {
            const int o = o_blk + owg * 16 + i * 16 + q * 4 + r;
            const size_t rowb = ((size_t)(bidx * 256 + o)) << 12;
            float ps = 0.f;
#pragma unroll
            for (int j = 0; j < 4; ++j) {
                float v = fmaxf(acc[i][j][r] + bia[i][r], 0.f);
                const size_t oi = rowb + pin0 + j * 16;
                if (OUTBF) ((u16*)outp)[oi] = f2bf(v);
                else       ((float*)outp)[oi] = v;
                ps += v;
            }
            if (DOPOOL) {   // reduce 64-px partial across the 16-lane px group
                ps += __shfl_down(ps, 8, 16);
                ps += __shfl_down(ps, 4, 16);
                ps += __shfl_down(ps, 2, 16);
                ps += __shfl_down(ps, 1, 16);
                if (r16 == 0)
                    atomicAdd(&poolp[(bidx << 9) + 256 + o], ps * (1.f / 4096.f));
            }
        }
    }
}

// ---------------- region dot products (partial over 64-ch group) ----------------
// np is NOT computed: n_k(p) = dot4(p+off_k) (center-norm plane, k=4).
__global__ __launch_bounds__(256) void k_sim(
    const u16* __restrict__ fe, float* __restrict__ pd)
{
    __shared__ __align__(16) u16 st[3 * 4096];   // [r][c][px]
    __shared__ float red[4][64][9];
    const int t = threadIdx.x;
    const int id = blockIdx.x;
    const int g = id & 3, h = (id >> 2) & 63, b = id >> 8;
    const int rows[3] = {h > 0 ? h - 1 : 0, h, h < 63 ? h + 1 : 63};
    const u16* base = fe + (((size_t)(b * 256 + g * 64)) << 12);
#pragma unroll
    for (int it = 0; it < 6; ++it) {
        const int flat = it * 256 + t;
        const int r = flat >> 9, j = flat & 511;     // j = c*8 + chunk
        const u16* gs = base + ((size_t)(j >> 3) << 12) + rows[r] * 64 + (j & 7) * 8;
        ld_g2l_16(st + r * 4096 + j * 8, gs);
    }
    __syncthreads();
    const int w = t & 63, sl = t >> 6;
    const int wl = w > 0 ? w - 1 : 0, wr = w < 63 ? w + 1 : 63;
    float dot[9] = {};
    const u16* s0 = st + sl * 16 * 64;
#pragma unroll 4
    for (int ci = 0; ci < 16; ++ci) {
        const u16* pc = s0 + ci * 64;
        float v[9];
#pragma unroll
        for (int r = 0; r < 3; ++r) {
            v[r * 3 + 0] = bf2f(pc[r * 4096 + wl]);
            v[r * 3 + 1] = bf2f(pc[r * 4096 + w]);
            v[r * 3 + 2] = bf2f(pc[r * 4096 + wr]);
        }
        const float c0 = v[4];
#pragma unroll
        for (int k = 0; k < 9; ++k) dot[k] = fmaf(c0, v[k], dot[k]);
    }
#pragma unroll
    for (int k = 0; k < 9; ++k) red[sl][w][k] = dot[k];
    __syncthreads();
    if (t < 64) {
        const int p = h * 64 + w;
#pragma unroll
        for (int k = 0; k < 9; ++k) {
            float s = red[0][w][k] + red[1][w][k] + red[2][w][k] + red[3][w][k];
            atomicAdd(&pd[((size_t)(b * 9 + k) << 12) + p], s);
        }
    }
}

// ---------------- softmax (fused) + aggregation; writes bf16 into xb[:,256:512] ----------------
// Stored weight = border_mask * softmax (softmax denom over all 9 entries,
// matching the reference where OOB terms have xpats==0).
__global__ __launch_bounds__(256) void k_agg(
    const u16* __restrict__ xb, const float* __restrict__ pd,
    u16* __restrict__ xbo)
{
    __shared__ __align__(16) u16 xt[3 * 4096];   // [r][px][c]
    __shared__ float ws9[9][64];
    const int t = threadIdx.x;
    const int id = blockIdx.x;
    const int g = id & 3, h = (id >> 2) & 63, b = id >> 8;
    const int rows[3] = {h > 0 ? h - 1 : 0, h, h < 63 ? h + 1 : 63};
    const u16* base = xb + (((size_t)(b * 4096)) << 9) + g * 64;
#pragma unroll
    for (int it = 0; it < 6; ++it) {
        const int flat = it * 256 + t;
        const int r = flat >> 9, j = flat & 511;     // j = px*8 + chunk
        const u16* gs = base + (((size_t)(rows[r] * 64 + (j >> 3))) << 9) + (j & 7) * 8;
        ld_g2l_16(xt + r * 4096 + j * 8, gs);
    }
    if (t < 64) {
        const int w = t;
        const int p = h * 64 + w;
        const float* pb = pd + (((size_t)(b * 9)) << 12);
        const float nc = sqrtf(pb[(4 << 12) + p]);
        float s[9], mk[9];
#pragma unroll
        for (int di = -1; di <= 1; ++di)
#pragma unroll
            for (int dj = -1; dj <= 1; ++dj) {
                const int k = (di + 1) * 3 + (dj + 1);
                const int hn = h + di, wn = w + dj;
                const float mask = (hn >= 0 && hn < 64 && wn >= 0 && wn < 64) ? 1.f : 0.f;
                const int hc = hn < 0 ? 0 : (hn > 63 ? 63 : hn);
                const int wc = wn < 0 ? 0 : (wn > 63 ? 63 : wn);
                const float nk = pb[(4 << 12) + hc * 64 + wc];
                const float dk = pb[(k << 12) + p];
                mk[k] = mask;
                s[k] = mask * dk / (nc * sqrtf(nk) + 1e-7f);
            }
        float mx = s[0];
#pragma unroll
        for (int k = 1; k < 9; ++k) mx = fmaxf(mx, s[k]);
        float e[9], sum = 0.f;
#pragma unroll
        for (int k = 0; k < 9; ++k) { e[k] = expf(s[k] - mx); sum += e[k]; }
        const float rs = 1.f / sum;
#pragma unroll
        for (int k = 0; k < 9; ++k) ws9[k][w] = mk[k] * e[k] * rs;   // masked weight
    }
    __syncthreads();
    const int c = t & 63, pg = t >> 6;   // 16 px per thread, lane = channel
    u16* orow = xbo + (((size_t)(b * 4096 + h * 64)) << 9) + 256 + g * 64 + c;
#pragma unroll 4
    for (int pi = 0; pi < 16; ++pi) {
        const int px = pg * 16 + pi;
        const int pl = px > 0 ? px - 1 : 0, pr = px < 63 ? px + 1 : 63;
        const int pxs[3] = {pl, px, pr};
        float m[9];
#pragma unroll
        for (int k = 0; k < 9; ++k) m[k] = ws9[k][px];
        float acc = 0.f;
#pragma unroll
        for (int r = 0; r < 3; ++r)
#pragma unroll
            for (int j = 0; j < 3; ++j)
                acc = fmaf(bf2f(xt[r * 4096 + pxs[j] * 64 + c]), m[r * 3 + j], acc);
        orow[(size_t)px << 9] = f2bf(acc);
    }
}

// ---------------- SE-style gate MLP ----------------
__global__ __launch_bounds__(64) void k_mlp(
    const float* __restrict__ pool,
    const float* __restrict__ wg1, const float* __restrict__ bg1,
    const float* __restrict__ wg2, const float* __restrict__ bg2,
    float* __restrict__ gate)
{
    __shared__ float pl[512];
    __shared__ float hb[64];
    const int b = blockIdx.x, t = threadIdx.x;
    for (int i = t; i < 512; i += 64) pl[i] = pool[b * 512 + i];
    __syncthreads();
    float s = bg1[t];
    const float* wr = wg1 + t * 512;
    for (int c = 0; c < 512; ++c) s = fmaf(wr[c], pl[c], s);
    hb[t] = fmaxf(s, 0.f);
    __syncthreads();
#pragma unroll
    for (int rr = 0; rr < 4; ++rr) {
        const int o = t + rr * 64;
        float s2 = bg2[o];
        const float* w2 = wg2 + o * 64;
        for (int j = 0; j < 64; ++j) s2 = fmaf(w2[j], hb[j], s2);
        gate[b * 256 + o] = 1.f / (1.f + expf(-s2));
    }
}

// ---------------- final: out = x + gate * enhanced (enh in bf16) ----------------
__global__ __launch_bounds__(256) void k_final(
    const float* __restrict__ x, const u16* __restrict__ enh,
    const float* __restrict__ gate, float* __restrict__ out)
{
    const int idx = blockIdx.x * 256 + threadIdx.x;
    const int e = idx << 2;
    const int b = e >> 20;
    const int c = (e >> 12) & 255;
    const float g = gate[b * 256 + c];
    float4 xv = *(const float4*)(x + e);
    ushort4 ev = *(const ushort4*)(enh + e);
    float4 rres;
    rres.x = fmaf(g, bf2f(ev.x), xv.x);
    rres.y = fmaf(g, bf2f(ev.y), xv.y);
    rres.z = fmaf(g, bf2f(ev.z), xv.z);
    rres.w = fmaf(g, bf2f(ev.w), xv.w);
    *(float4*)(out + e) = rres;
}

extern "C" void kernel_launch(void* const* d_in, const int* in_sizes, int n_in,
                              void* d_out, int out_size, void* d_ws, size_t ws_size,
                              hipStream_t stream)
{
    const float* x       = (const float*)d_in[0];
    const float* w_embed = (const float*)d_in[1];
    const float* b_embed = (const float*)d_in[2];
    const float* g1      = (const float*)d_in[3];
    const float* be1     = (const float*)d_in[4];
    const float* m1      = (const float*)d_in[5];
    const float* v1      = (const float*)d_in[6];
    const float* w_enh   = (const float*)d_in[7];
    const float* b_enh   = (const float*)d_in[8];
    const float* g2      = (const float*)d_in[9];
    const float* be2     = (const float*)d_in[10];
    const float* m2      = (const float*)d_in[11];
    const float* v2      = (const float*)d_in[12];
    const float* w_g1    = (const float*)d_in[13];
    const float* b_g1    = (const float*)d_in[14];
    const float* w_g2    = (const float*)d_in[15];
    const float* b_g2    = (const float*)d_in[16];
    float* ws  = (float*)d_ws;
    float* out = (float*)d_out;

    u16*   xb   = (u16*)(ws + OFS_XB);
    float* pd   = ws + OFS_PD;
    u16*   w1b  = (u16*)(ws + OFS_W1B);
    u16*   w2b  = (u16*)(ws + OFS_W2B);
    float* b1f  = ws + OFS_B1;
    float* b2f  = ws + OFS_B2;
    float* pool = ws + OFS_POOL;
    float* gate = ws + OFS_GATE;
    u16*   enh  = (u16*)(ws + OFS_ENH);
    u16*   fe   = (u16*)d_out;   // fe (bf16) lives in d_out; dead before k_final writes

    k_prep<<<dim3(1062), dim3(256), 0, stream>>>(
        w_embed, b_embed, g1, be1, m1, v1,
        w_enh, b_enh, g2, be2, m2, v2, w1b, w2b, b1f, b2f, pd, pool);
    k_cvt<<<dim3(2048), dim3(256), 0, stream>>>(x, xb, pool);
    k_gemm<256, true, false><<<dim3(256, 2), dim3(256), 0, stream>>>(xb, w1b, b1f, (void*)fe, nullptr);
    k_sim<<<dim3(2048), dim3(256), 0, stream>>>(fe, pd);
    k_agg<<<dim3(2048), dim3(256), 0, stream>>>(xb, pd, xb);
    k_gemm<512, true, true><<<dim3(256, 2), dim3(256), 0, stream>>>(xb, w2b, b2f, (void*)enh, pool);
    k_mlp<<<dim3(8), dim3(64), 0, stream>>>(pool, w_g1, b_g1, w_g2, b_g2, gate);
    k_final<<<dim3(8192), dim3(256), 0, stream>>>(x, enh, gate, out);
}